// Round 3
// baseline (52.073 us; speedup 1.0000x reference)
//
#include <hip/hip_runtime.h>

// Problem constants (from reference): B=8, L=4096, D=1024, MAX_CHUNKS=128
#define B_DIM 8
#define L_DIM 4096
#define D_DIM 1024
#define MAXC 128
#define ROWS 32                       // rows per tile in pool kernel
#define TILES_PER_B (L_DIM / ROWS)    // 128

__device__ __forceinline__ void f4add(float4& a, const float4& v) {
    a.x += v.x; a.y += v.y; a.z += v.z; a.w += v.w;
}

// ---------------------------------------------------------------------------
// Kernel A: per batch (8 blocks x 256 threads):
//   - threshold boundaries, block scan -> seg id per token (clamped: tokens
//     before first boundary and seg>=MAXC -> trash id MAXC), written to seg[]
//   - boundary positions kept in LDS -> per-chunk counts written to cnts[]
// ---------------------------------------------------------------------------
__global__ void boundaries_kernel(const float* __restrict__ bnd,
                                  int* __restrict__ seg,    // [B][L]
                                  int* __restrict__ cnts)   // [B][MAXC]
{
    const int b = blockIdx.x;
    const int t = threadIdx.x;           // 0..255
    const float* p = bnd + (size_t)b * L_DIM;
    const int base = t * 16;

    unsigned m = 0u;
#pragma unroll
    for (int j = 0; j < 16; ++j) {
        m |= (p[base + j] > 0.5f) ? (1u << j) : 0u;
    }
    int cnt = __popc(m);

    __shared__ int s[256];
    __shared__ int spos[L_DIM];          // boundary positions (worst case L)
    s[t] = cnt;
    __syncthreads();
    for (int off = 1; off < 256; off <<= 1) {
        int v = (t >= off) ? s[t - off] : 0;
        __syncthreads();
        s[t] += v;
        __syncthreads();
    }
    const int excl = s[t] - cnt;
    const int n    = s[255];

    // boundary positions into LDS
    {
        int idx = excl;
#pragma unroll
        for (int j = 0; j < 16; ++j) {
            if (m & (1u << j)) spos[idx++] = base + j;
        }
    }

    // per-token segment ids (packed int4 stores)
    {
        int c = excl;
        int4* sp = reinterpret_cast<int4*>(seg + (size_t)b * L_DIM + base);
#pragma unroll
        for (int q = 0; q < 4; ++q) {
            int4 w;
            int vals[4];
#pragma unroll
            for (int j = 0; j < 4; ++j) {
                if (m & (1u << (q * 4 + j))) ++c;
                int sv = c - 1;
                vals[j] = (sv < 0 || sv >= MAXC) ? MAXC : sv;
            }
            w.x = vals[0]; w.y = vals[1]; w.z = vals[2]; w.w = vals[3];
            sp[q] = w;
        }
    }
    __syncthreads();

    // per-chunk counts
    if (t < MAXC) {
        int cn = 0;
        if (t < n) {
            const int start = spos[t];
            const int end   = (t + 1 < n) ? spos[t + 1] : L_DIM;
            cn = end - start;
        }
        cnts[b * MAXC + t] = cn;
    }
}

// ---------------------------------------------------------------------------
// Kernel B: balanced pooling. One block per 32-row tile (1024 identical
// blocks). Each thread owns a float4 column slice; accumulates consecutive
// rows sharing a segment id in registers and flushes partial sums into the
// output buffer via atomicAdd (out was zeroed). Branches are block-uniform.
// ---------------------------------------------------------------------------
__global__ void pool_tiles_kernel(const float* __restrict__ x,
                                  const int* __restrict__ seg,
                                  float* __restrict__ out_sums) // [B][MAXC][D]
{
    const int tile = blockIdx.x;               // 0 .. B*TILES_PER_B-1
    const int b    = tile >> 7;                // / TILES_PER_B (=128)
    const int r0   = (tile & (TILES_PER_B - 1)) * ROWS;
    const int t    = threadIdx.x;              // 0..255

    __shared__ int sseg[ROWS];
    if (t < ROWS) sseg[t] = seg[(size_t)b * L_DIM + r0 + t];
    __syncthreads();

    const float* xp = x + ((size_t)b * L_DIM + r0) * D_DIM + t * 4;

    float4 acc = make_float4(0.f, 0.f, 0.f, 0.f);
    int cur = sseg[0];

    for (int rr = 0; rr < ROWS; rr += 8) {
        float4 vbuf[8];
#pragma unroll
        for (int j = 0; j < 8; ++j) {
            vbuf[j] = *reinterpret_cast<const float4*>(xp + (size_t)(rr + j) * D_DIM);
        }
#pragma unroll
        for (int j = 0; j < 8; ++j) {
            const int s = sseg[rr + j];
            if (s != cur) {
                if (cur < MAXC) {
                    float* d = out_sums + ((size_t)b * MAXC + cur) * D_DIM + t * 4;
                    atomicAdd(d + 0, acc.x);
                    atomicAdd(d + 1, acc.y);
                    atomicAdd(d + 2, acc.z);
                    atomicAdd(d + 3, acc.w);
                }
                acc = make_float4(0.f, 0.f, 0.f, 0.f);
                cur = s;
            }
            f4add(acc, vbuf[j]);
        }
    }
    if (cur < MAXC) {
        float* d = out_sums + ((size_t)b * MAXC + cur) * D_DIM + t * 4;
        atomicAdd(d + 0, acc.x);
        atomicAdd(d + 1, acc.y);
        atomicAdd(d + 2, acc.z);
        atomicAdd(d + 3, acc.w);
    }
}

// ---------------------------------------------------------------------------
// Kernel C: in-place sums -> means; write counts as floats to the tail.
// ---------------------------------------------------------------------------
__global__ void finalize_kernel(float* __restrict__ out_means,  // [B][MAXC][D]
                                const int* __restrict__ cnts,   // [B][MAXC]
                                float* __restrict__ out_cnts)   // [B][MAXC]
{
    const int bc = blockIdx.x;          // 0 .. B*MAXC-1
    const int t  = threadIdx.x;         // 0..255
    const int cn = cnts[bc];
    const float inv = (cn > 0) ? (1.0f / (float)cn) : 0.0f;

    float4* o4 = reinterpret_cast<float4*>(out_means + (size_t)bc * D_DIM) + t;
    float4 v = *o4;
    v.x *= inv; v.y *= inv; v.z *= inv; v.w *= inv;
    *o4 = v;

    if (t == 0) out_cnts[bc] = (float)cn;
}

extern "C" void kernel_launch(void* const* d_in, const int* in_sizes, int n_in,
                              void* d_out, int out_size, void* d_ws, size_t ws_size,
                              hipStream_t stream)
{
    const float* x   = (const float*)d_in[0];   // [B, L, D] fp32
    const float* bnd = (const float*)d_in[1];   // [B, L]    fp32

    float* out = (float*)d_out;
    float* out_means = out;                                // B*MAXC*D floats
    float* out_cnts  = out + (size_t)B_DIM * MAXC * D_DIM; // B*MAXC floats

    // workspace: seg[B][L] ints, cnts[B][MAXC] ints (~132 KB)
    int* seg  = (int*)d_ws;
    int* cnts = seg + (size_t)B_DIM * L_DIM;

    // zero the output (sums accumulate into it via atomics)
    hipMemsetAsync(d_out, 0, (size_t)out_size * sizeof(float), stream);

    boundaries_kernel<<<B_DIM, 256, 0, stream>>>(bnd, seg, cnts);
    pool_tiles_kernel<<<B_DIM * TILES_PER_B, 256, 0, stream>>>(x, seg, out_means);
    finalize_kernel<<<B_DIM * MAXC, 256, 0, stream>>>(out_means, cnts, out_cnts);
}

// Round 4
// 51.388 us; speedup vs baseline: 1.0133x; 1.0133x over previous
//
#include <hip/hip_runtime.h>

// Problem constants (from reference): B=8, L=4096, D=1024, MAX_CHUNKS=128
#define B_DIM 8
#define L_DIM 4096
#define D_DIM 1024
#define MAXC 128
#define ROWS 32                       // rows per tile in pool kernel
#define TILES_PER_B (L_DIM / ROWS)    // 128

__device__ __forceinline__ void f4add(float4& a, const float4& v) {
    a.x += v.x; a.y += v.y; a.z += v.z; a.w += v.w;
}

// ---------------------------------------------------------------------------
// Zero the means region of d_out (atomic accumulation base). 4 MB, one
// float4 per thread, 1024 blocks -- stays in L2/L3, ~2-4 us.
// ---------------------------------------------------------------------------
__global__ void zero_means_kernel(float4* __restrict__ out4)
{
    const size_t i = (size_t)blockIdx.x * blockDim.x + threadIdx.x;
    out4[i] = make_float4(0.f, 0.f, 0.f, 0.f);
}

// ---------------------------------------------------------------------------
// Kernel A: per batch (8 blocks x 256 threads):
//   - threshold boundaries, block scan -> seg id per token (clamped: tokens
//     before first boundary and seg>=MAXC -> trash id MAXC), written to seg[]
//   - boundary positions kept in LDS -> per-chunk counts written to cnts[]
// ---------------------------------------------------------------------------
__global__ void boundaries_kernel(const float* __restrict__ bnd,
                                  int* __restrict__ seg,    // [B][L]
                                  int* __restrict__ cnts)   // [B][MAXC]
{
    const int b = blockIdx.x;
    const int t = threadIdx.x;           // 0..255
    const float* p = bnd + (size_t)b * L_DIM;
    const int base = t * 16;

    unsigned m = 0u;
#pragma unroll
    for (int j = 0; j < 16; ++j) {
        m |= (p[base + j] > 0.5f) ? (1u << j) : 0u;
    }
    int cnt = __popc(m);

    __shared__ int s[256];
    __shared__ int spos[L_DIM];          // boundary positions (worst case L)
    s[t] = cnt;
    __syncthreads();
    for (int off = 1; off < 256; off <<= 1) {
        int v = (t >= off) ? s[t - off] : 0;
        __syncthreads();
        s[t] += v;
        __syncthreads();
    }
    const int excl = s[t] - cnt;
    const int n    = s[255];

    // boundary positions into LDS
    {
        int idx = excl;
#pragma unroll
        for (int j = 0; j < 16; ++j) {
            if (m & (1u << j)) spos[idx++] = base + j;
        }
    }

    // per-token segment ids (packed int4 stores)
    {
        int c = excl;
        int4* sp = reinterpret_cast<int4*>(seg + (size_t)b * L_DIM + base);
#pragma unroll
        for (int q = 0; q < 4; ++q) {
            int4 w;
            int vals[4];
#pragma unroll
            for (int j = 0; j < 4; ++j) {
                if (m & (1u << (q * 4 + j))) ++c;
                int sv = c - 1;
                vals[j] = (sv < 0 || sv >= MAXC) ? MAXC : sv;
            }
            w.x = vals[0]; w.y = vals[1]; w.z = vals[2]; w.w = vals[3];
            sp[q] = w;
        }
    }
    __syncthreads();

    // per-chunk counts
    if (t < MAXC) {
        int cn = 0;
        if (t < n) {
            const int start = spos[t];
            const int end   = (t + 1 < n) ? spos[t + 1] : L_DIM;
            cn = end - start;
        }
        cnts[b * MAXC + t] = cn;
    }
}

// ---------------------------------------------------------------------------
// Kernel B: balanced pooling. One block per 32-row tile (1024 identical
// blocks). Each thread owns a float4 column slice; accumulates consecutive
// rows sharing a segment id in registers and flushes partial sums into the
// output buffer via atomicAdd (out was zeroed). Branches are block-uniform.
// ---------------------------------------------------------------------------
__global__ void pool_tiles_kernel(const float* __restrict__ x,
                                  const int* __restrict__ seg,
                                  float* __restrict__ out_sums) // [B][MAXC][D]
{
    const int tile = blockIdx.x;               // 0 .. B*TILES_PER_B-1
    const int b    = tile >> 7;                // / TILES_PER_B (=128)
    const int r0   = (tile & (TILES_PER_B - 1)) * ROWS;
    const int t    = threadIdx.x;              // 0..255

    __shared__ int sseg[ROWS];
    if (t < ROWS) sseg[t] = seg[(size_t)b * L_DIM + r0 + t];
    __syncthreads();

    const float* xp = x + ((size_t)b * L_DIM + r0) * D_DIM + t * 4;

    float4 acc = make_float4(0.f, 0.f, 0.f, 0.f);
    int cur = sseg[0];

    for (int rr = 0; rr < ROWS; rr += 8) {
        float4 vbuf[8];
#pragma unroll
        for (int j = 0; j < 8; ++j) {
            vbuf[j] = *reinterpret_cast<const float4*>(xp + (size_t)(rr + j) * D_DIM);
        }
#pragma unroll
        for (int j = 0; j < 8; ++j) {
            const int s = sseg[rr + j];
            if (s != cur) {
                if (cur < MAXC) {
                    float* d = out_sums + ((size_t)b * MAXC + cur) * D_DIM + t * 4;
                    atomicAdd(d + 0, acc.x);
                    atomicAdd(d + 1, acc.y);
                    atomicAdd(d + 2, acc.z);
                    atomicAdd(d + 3, acc.w);
                }
                acc = make_float4(0.f, 0.f, 0.f, 0.f);
                cur = s;
            }
            f4add(acc, vbuf[j]);
        }
    }
    if (cur < MAXC) {
        float* d = out_sums + ((size_t)b * MAXC + cur) * D_DIM + t * 4;
        atomicAdd(d + 0, acc.x);
        atomicAdd(d + 1, acc.y);
        atomicAdd(d + 2, acc.z);
        atomicAdd(d + 3, acc.w);
    }
}

// ---------------------------------------------------------------------------
// Kernel C: in-place sums -> means; write counts as floats to the tail.
// ---------------------------------------------------------------------------
__global__ void finalize_kernel(float* __restrict__ out_means,  // [B][MAXC][D]
                                const int* __restrict__ cnts,   // [B][MAXC]
                                float* __restrict__ out_cnts)   // [B][MAXC]
{
    const int bc = blockIdx.x;          // 0 .. B*MAXC-1
    const int t  = threadIdx.x;         // 0..255
    const int cn = cnts[bc];
    const float inv = (cn > 0) ? (1.0f / (float)cn) : 0.0f;

    float4* o4 = reinterpret_cast<float4*>(out_means + (size_t)bc * D_DIM) + t;
    float4 v = *o4;
    v.x *= inv; v.y *= inv; v.z *= inv; v.w *= inv;
    *o4 = v;

    if (t == 0) out_cnts[bc] = (float)cn;
}

extern "C" void kernel_launch(void* const* d_in, const int* in_sizes, int n_in,
                              void* d_out, int out_size, void* d_ws, size_t ws_size,
                              hipStream_t stream)
{
    const float* x   = (const float*)d_in[0];   // [B, L, D] fp32
    const float* bnd = (const float*)d_in[1];   // [B, L]    fp32

    float* out = (float*)d_out;
    float* out_means = out;                                // B*MAXC*D floats
    float* out_cnts  = out + (size_t)B_DIM * MAXC * D_DIM; // B*MAXC floats

    // workspace: seg[B][L] ints, cnts[B][MAXC] ints (~132 KB)
    int* seg  = (int*)d_ws;
    int* cnts = seg + (size_t)B_DIM * L_DIM;

    // zero the means region with our own kernel (runtime fill kernel is ~75us)
    // B*MAXC*D floats = 1,048,576 floats = 262,144 float4 = 1024 blocks * 256
    zero_means_kernel<<<(B_DIM * MAXC * D_DIM / 4 + 255) / 256, 256, 0, stream>>>(
        reinterpret_cast<float4*>(out_means));

    boundaries_kernel<<<B_DIM, 256, 0, stream>>>(bnd, seg, cnts);
    pool_tiles_kernel<<<B_DIM * TILES_PER_B, 256, 0, stream>>>(x, seg, out_means);
    finalize_kernel<<<B_DIM * MAXC, 256, 0, stream>>>(out_means, cnts, out_cnts);
}

// Round 5
// 34.446 us; speedup vs baseline: 1.5117x; 1.4918x over previous
//
#include <hip/hip_runtime.h>

// Problem constants (from reference): B=8, L=4096, D=1024, MAX_CHUNKS=128
#define B_DIM 8
#define L_DIM 4096
#define D_DIM 1024
#define MAXC 128
#define RG 4            // row groups per block
#define CT 256          // column threads (D/4 float4 slices)

__device__ __forceinline__ void f4add(float4& a, const float4& v) {
    a.x += v.x; a.y += v.y; a.z += v.z; a.w += v.w;
}

// ---------------------------------------------------------------------------
// Kernel A: per batch, find boundary positions (boundaries > 0.5) in order.
// 256 threads/block, each thread owns 16 contiguous elements of the row.
// Block-wide Hillis-Steele scan gives each thread its write offset.
// ---------------------------------------------------------------------------
__global__ void find_boundaries_kernel(const float* __restrict__ bnd,
                                       int* __restrict__ pos,   // [B][L]
                                       int* __restrict__ nseg)  // [B]
{
    const int b = blockIdx.x;
    const int t = threadIdx.x;           // 0..255
    const float* p = bnd + (size_t)b * L_DIM;
    const int base = t * 16;

    unsigned m = 0u;
#pragma unroll
    for (int j = 0; j < 16; ++j) {
        m |= (p[base + j] > 0.5f) ? (1u << j) : 0u;
    }
    int cnt = __popc(m);

    __shared__ int s[256];
    s[t] = cnt;
    __syncthreads();
    for (int off = 1; off < 256; off <<= 1) {
        int v = (t >= off) ? s[t - off] : 0;
        __syncthreads();
        s[t] += v;
        __syncthreads();
    }
    int excl = s[t] - cnt;
    int* op = pos + (size_t)b * L_DIM;
    int idx = excl;
#pragma unroll
    for (int j = 0; j < 16; ++j) {
        if (m & (1u << j)) op[idx++] = base + j;
    }
    if (t == 255) nseg[b] = s[255];
}

// ---------------------------------------------------------------------------
// Kernel B: one block per (batch, chunk), 1024 threads = 4 row-groups x 256
// column threads. Row-group rg accumulates rows rg, rg+4, rg+8, ... with 8
// independent accumulator chains (peeled remainder also independent), then
// LDS-reduce across the 4 groups. Cuts the longest-chunk serial chain 4x vs
// the 256-thread version. Direct (non-atomic) output writes; empty chunks
// write zeros (d_out is poisoned by the harness).
// ---------------------------------------------------------------------------
__global__ __launch_bounds__(1024)
void pool_chunks_kernel(const float* __restrict__ x,
                        const int* __restrict__ pos,
                        const int* __restrict__ nseg,
                        float* __restrict__ out_means,  // [B][MAXC][D]
                        float* __restrict__ out_cnts)   // [B][MAXC]
{
    const int bc = blockIdx.x;          // 0 .. B*MAXC-1
    const int b  = bc >> 7;             // / MAXC
    const int c  = bc & (MAXC - 1);
    const int t  = threadIdx.x;         // 0..1023
    const int tc = t & (CT - 1);        // column thread 0..255
    const int rg = t >> 8;              // row group 0..3

    __shared__ float4 red[RG][CT];      // 16 KB

    const int n = nseg[b];
    int cnt = 0;

    float4 a0 = make_float4(0.f, 0.f, 0.f, 0.f);
    float4 a1 = a0, a2 = a0, a3 = a0, a4 = a0, a5 = a0, a6 = a0, a7 = a0;

    if (c < n) {
        const int* pp = pos + (size_t)b * L_DIM;
        const int start = pp[c];
        const int end   = (c + 1 < n) ? pp[c + 1] : L_DIM;
        cnt = end - start;

        // this group's rows: r = rg + RG*k, k in [0, nr)
        const int nr = (cnt - rg + RG - 1) / RG;          // >=0 always
        const float* xp = x + ((size_t)b * L_DIM + start + rg) * D_DIM + tc * 4;
        const size_t stride = (size_t)RG * D_DIM;         // floats between rows

        int k = 0;
        const int rem = nr & 7;
        // peeled remainder: all chains independent
        if (rem & 4) {
            float4 v0 = *reinterpret_cast<const float4*>(xp + (size_t)(k + 0) * stride);
            float4 v1 = *reinterpret_cast<const float4*>(xp + (size_t)(k + 1) * stride);
            float4 v2 = *reinterpret_cast<const float4*>(xp + (size_t)(k + 2) * stride);
            float4 v3 = *reinterpret_cast<const float4*>(xp + (size_t)(k + 3) * stride);
            f4add(a0, v0); f4add(a1, v1); f4add(a2, v2); f4add(a3, v3);
            k += 4;
        }
        if (rem & 2) {
            float4 v0 = *reinterpret_cast<const float4*>(xp + (size_t)(k + 0) * stride);
            float4 v1 = *reinterpret_cast<const float4*>(xp + (size_t)(k + 1) * stride);
            f4add(a4, v0); f4add(a5, v1);
            k += 2;
        }
        if (rem & 1) {
            float4 v0 = *reinterpret_cast<const float4*>(xp + (size_t)k * stride);
            f4add(a6, v0);
            k += 1;
        }
        // main loop: 8 rows per iteration, 8 independent chains
        for (; k + 8 <= nr; k += 8) {
            const float* base = xp + (size_t)k * stride;
            float4 v0 = *reinterpret_cast<const float4*>(base + 0 * stride);
            float4 v1 = *reinterpret_cast<const float4*>(base + 1 * stride);
            float4 v2 = *reinterpret_cast<const float4*>(base + 2 * stride);
            float4 v3 = *reinterpret_cast<const float4*>(base + 3 * stride);
            float4 v4 = *reinterpret_cast<const float4*>(base + 4 * stride);
            float4 v5 = *reinterpret_cast<const float4*>(base + 5 * stride);
            float4 v6 = *reinterpret_cast<const float4*>(base + 6 * stride);
            float4 v7 = *reinterpret_cast<const float4*>(base + 7 * stride);
            f4add(a0, v0); f4add(a1, v1); f4add(a2, v2); f4add(a3, v3);
            f4add(a4, v4); f4add(a5, v5); f4add(a6, v6); f4add(a7, v7);
        }
        f4add(a0, a1); f4add(a2, a3); f4add(a4, a5); f4add(a6, a7);
        f4add(a0, a2); f4add(a4, a6);
        f4add(a0, a4);
    }

    red[rg][tc] = a0;
    __syncthreads();

    if (t < CT) {
        float4 s0 = red[0][t];
        f4add(s0, red[1][t]);
        f4add(s0, red[2][t]);
        f4add(s0, red[3][t]);
        const float inv = (cnt > 0) ? (1.0f / (float)cnt) : 0.0f;
        s0.x *= inv; s0.y *= inv; s0.z *= inv; s0.w *= inv;
        float4* op = reinterpret_cast<float4*>(out_means + (size_t)bc * D_DIM) + t;
        *op = s0;
        if (t == 0) out_cnts[bc] = (float)cnt;
    }
}

extern "C" void kernel_launch(void* const* d_in, const int* in_sizes, int n_in,
                              void* d_out, int out_size, void* d_ws, size_t ws_size,
                              hipStream_t stream)
{
    const float* x   = (const float*)d_in[0];   // [B, L, D] fp32
    const float* bnd = (const float*)d_in[1];   // [B, L]    fp32

    float* out = (float*)d_out;
    float* out_means = out;                                // B*MAXC*D floats
    float* out_cnts  = out + (size_t)B_DIM * MAXC * D_DIM; // B*MAXC floats

    // workspace layout: pos[B][L] ints, then nseg[B] ints
    int* pos  = (int*)d_ws;
    int* nseg = pos + (size_t)B_DIM * L_DIM;

    find_boundaries_kernel<<<B_DIM, 256, 0, stream>>>(bnd, pos, nseg);
    pool_chunks_kernel<<<B_DIM * MAXC, 1024, 0, stream>>>(x, pos, nseg,
                                                          out_means, out_cnts);
}